// Round 7
// baseline (193.300 us; speedup 1.0000x reference)
//
#include <hip/hip_runtime.h>

typedef unsigned short u16;
typedef __attribute__((ext_vector_type(8))) short bf16x8;
typedef __attribute__((ext_vector_type(4))) float f32x4;
typedef __attribute__((ext_vector_type(16))) float f32x16;
typedef __attribute__((ext_vector_type(2))) unsigned int u32x2;

__device__ inline u16 f2b(float f) {
    unsigned u;
    __builtin_memcpy(&u, &f, 4);
    unsigned r = u + 0x7FFF + ((u >> 16) & 1);  // RNE
    return (u16)(r >> 16);
}

__device__ inline bf16x8 pack8(const float* p) {
    union { u16 us[8]; bf16x8 v; } r;
#pragma unroll
    for (int i = 0; i < 8; i++) r.us[i] = f2b(p[i]);
    return r.v;
}

// packed 2xf32 -> 2xbf16 (RNE), src0 -> low half
__device__ inline unsigned cvtpk(float lo, float hi) {
    unsigned r;
    asm("v_cvt_pk_bf16_f32 %0, %1, %2" : "=v"(r) : "v"(lo), "v"(hi));
    return r;
}

// async global->LDS, 16B per lane. LDS dest is wave-uniform base + lane*16;
// the GLOBAL source per lane is arbitrary (this is what makes the XOR-swizzle
// staging below possible).
__device__ inline void gload16(const void* g, void* l) {
    __builtin_amdgcn_global_load_lds((__attribute__((address_space(1))) void*)g,
                                     (__attribute__((address_space(3))) void*)l, 16, 0, 0);
}

// ---------------------------------------------------------------------------
// One-shot fp32 -> bf16: x (4096 blocks) then wq,wk,wv,wo (128 each) into wb.
// ---------------------------------------------------------------------------
__global__ __launch_bounds__(256) void conv_kernel(const float* __restrict__ x,
                                                   const float* __restrict__ wq,
                                                   const float* __restrict__ wk,
                                                   const float* __restrict__ wv,
                                                   const float* __restrict__ wo,
                                                   u16* __restrict__ xb, u16* __restrict__ wb) {
    const int bid = blockIdx.x;
    const float* src;
    u16* dst;
    size_t base;
    if (bid < 4096) {
        src = x; dst = xb; base = (size_t)bid * 2048;
    } else {
        const int wsel = (bid - 4096) >> 7;
        src = (wsel == 0) ? wq : (wsel == 1) ? wk : (wsel == 2) ? wv : wo;
        dst = wb + (size_t)wsel * 262144;
        base = (size_t)((bid - 4096) & 127) * 2048;
    }
    const size_t idx = base + (size_t)threadIdx.x * 8;
    float a[8];
    *(float4*)&a[0] = *(const float4*)&src[idx];
    *(float4*)&a[4] = *(const float4*)&src[idx + 4];
    *(bf16x8*)&dst[idx] = pack8(a);
}

// ---------------------------------------------------------------------------
// bf16 GEMM v2: C[m][n] = sum_k A[m][k]*W[n][k] + bias[n].
// 128x128 tile, BK=32, 4 waves; double-buffered LDS + prefetch-before-compute
// + chunk-XOR LDS swizzle (see round-3 notes).
// MODE 0: N=1536 (q|k|v rows of wb); scatter Q*0.125,K -> (s,h,tok,hd),
//         V -> transposed (s,h,hd,tok). MODE 1: fp32 row-major out (d_out).
// ---------------------------------------------------------------------------
template <int MODE>
__global__ __launch_bounds__(256) void gemm_kernel(const u16* __restrict__ A,
                                                   const u16* __restrict__ W,
                                                   const float* __restrict__ B0,
                                                   const float* __restrict__ B1,
                                                   const float* __restrict__ B2,
                                                   void* __restrict__ O0v, u16* __restrict__ O1,
                                                   u16* __restrict__ O2) {
    const int m0 = blockIdx.x * 128;
    const int n0 = blockIdx.y * 128;
    const int seg = (MODE == 0) ? (n0 >> 9) : 0;
    const int nl0 = (MODE == 0) ? (n0 & 511) : n0;
    const float* Bb = (seg == 0) ? B0 : (seg == 1) ? B1 : B2;
    u16* O = (seg == 0) ? (u16*)O0v : (seg == 1) ? O1 : O2;

    __shared__ __align__(16) u16 Al[2][128 * 32];
    __shared__ __align__(16) u16 Bl[2][128 * 32];

    const int tid = threadIdx.x;
    const int lane = tid & 63, wave = tid >> 6;
    const int quad = lane >> 4, col = lane & 15;
    const int wm = wave >> 1, wn = wave & 1;

    // staging decode (hoisted): cl -> row, swizzled source chunk offset
    int srow[2], ssc[2];
#pragma unroll
    for (int i = 0; i < 2; i++) {
        const int cl = tid + i * 256;
        srow[i] = cl >> 2;
        ssc[i] = (((cl & 3) ^ ((srow[i] >> 1) & 3))) * 8;
    }
    // frag-read swizzle term: (row>>1)&3 == (col>>1)&3 for row = w*64+t*16+col
    const int cswz = quad ^ ((col >> 1) & 3);

#define GSTAGE(BUF, K0)                                                                   \
    {                                                                                     \
        _Pragma("unroll") for (int i_ = 0; i_ < 2; i_++) {                                \
            const int cl_ = tid + i_ * 256;                                               \
            gload16(&A[(size_t)(m0 + srow[i_]) * 512 + (K0) + ssc[i_]], &Al[BUF][cl_ * 8]); \
        }                                                                                 \
        _Pragma("unroll") for (int i_ = 0; i_ < 2; i_++) {                                \
            const int cl_ = tid + i_ * 256;                                               \
            gload16(&W[(size_t)(n0 + srow[i_]) * 512 + (K0) + ssc[i_]], &Bl[BUF][cl_ * 8]); \
        }                                                                                 \
    }

    f32x4 acc[4][4];
#pragma unroll
    for (int i = 0; i < 4; i++)
#pragma unroll
        for (int j = 0; j < 4; j++) acc[i][j] = (f32x4){0.f, 0.f, 0.f, 0.f};

    GSTAGE(0, 0)  // prologue
    __syncthreads();

    int bufi = 0;
    for (int k0 = 0; k0 < 512; k0 += 32) {
        if (k0 < 480) GSTAGE(bufi ^ 1, k0 + 32)  // prefetch overlaps compute below

        bf16x8 af[4], bfr[4];
#pragma unroll
        for (int t = 0; t < 4; t++) {
            af[t] = *(const bf16x8*)&Al[bufi][((wm * 64 + t * 16 + col) * 4 + cswz) * 8];
            bfr[t] = *(const bf16x8*)&Bl[bufi][((wn * 64 + t * 16 + col) * 4 + cswz) * 8];
        }
        __builtin_amdgcn_s_setprio(1);
#pragma unroll
        for (int i = 0; i < 4; i++)
#pragma unroll
            for (int j = 0; j < 4; j++)
                acc[i][j] = __builtin_amdgcn_mfma_f32_16x16x32_bf16(af[i], bfr[j], acc[i][j], 0, 0, 0);
        __builtin_amdgcn_s_setprio(0);
        __syncthreads();  // prefetch DMA drained here (overlapped with the MFMAs above)
        bufi ^= 1;
    }
#undef GSTAGE

    float bias[4];
#pragma unroll
    for (int j = 0; j < 4; j++) bias[j] = Bb[nl0 + wn * 64 + j * 16 + col];

#pragma unroll
    for (int i = 0; i < 4; i++) {
        const int mbase = m0 + wm * 64 + i * 16 + quad * 4;
#pragma unroll
        for (int j = 0; j < 4; j++) {
            const int nl = nl0 + wn * 64 + j * 16 + col;
            if (MODE == 1) {
                float* Of = (float*)O0v;  // fp32 final output
#pragma unroll
                for (int r = 0; r < 4; r++)
                    Of[(size_t)(mbase + r) * 512 + nl] = acc[i][j][r] + bias[j];
            } else {
                const int h = nl >> 6, hd = nl & 63;
                if (seg < 2) {
                    const float qs = (seg == 0) ? 0.125f : 1.f;  // pre-scale Q by 1/sqrt(64)
#pragma unroll
                    for (int r = 0; r < 4; r++) {
                        int m = mbase + r;
                        int s = m >> 10, tok = m & 1023;
                        O[(size_t)((s * 8 + h) * 1024 + tok) * 64 + hd] =
                            f2b((acc[i][j][r] + bias[j]) * qs);
                    }
                } else {
                    // V transposed: ((s*8+h)*64 + hd)*1024 + tok
                    int s = mbase >> 10, tok0 = mbase & 1023;
                    union { u16 us[4]; uint2 v; } pk;
#pragma unroll
                    for (int r = 0; r < 4; r++) pk.us[r] = f2b(acc[i][j][r] + bias[j]);
                    *(uint2*)&O[(size_t)((s * 8 + h) * 64 + hd) * 1024 + tok0] = pk.v;
                }
            }
        }
    }
}

// ---------------------------------------------------------------------------
// Attention v11 = v10 + intra-wave 2-stage software pipeline (T15-style).
// v10 counters showed MFMA busy (36%) + VALU busy (37%) ~= wall: the pipes
// run SERIALLY because (a) the per-mt chain QK->pack->PV is strictly
// dependent, (b) the 2 co-resident waves/SIMD are phase-locked. Fix: two
// score-register sets (A/B); issue QK(mt+1) MFMAs BEFORE pack(mt), so the
// pack VALU (and the vf ds_reads) execute underneath the in-flight MFMAs:
//   QK0->A; QK1->B; packPV(0,A); QK2->A; packPV(1,B); QK3->B; packPV(2,A);
//   packPV(3,B)
// All names static (rule #20). +32 VGPR for the second score set.
// 512 blocks x 4 waves, QBLK=64/wave, KVBLK=128, 2 blocks/CU, LDS 64KB.
// ---------------------------------------------------------------------------
__global__ __launch_bounds__(256, 2) void attn_kernel(const u16* __restrict__ Q,
                                                      const u16* __restrict__ Kp,
                                                      const u16* __restrict__ Vt,
                                                      u16* __restrict__ Ctx) {
    __shared__ __align__(16) u16 Kl[2][8192];  // [buf][128 keys x 64 hd], swizzled chunks
    __shared__ __align__(16) u16 Vl[2][8192];  // [buf][64 hd  x 128 tok], swizzled chunks

    const int bid = blockIdx.x;
    const int head = bid & 127;  // same-head blocks == mod 8 -> same XCD L2
    const int qt = bid >> 7;     // 0..3, 256 q-rows each
    const int s = head >> 3, h = head & 7;
    const u16* Qh = Q + (size_t)head * 65536;
    const u16* Kh = Kp + (size_t)head * 65536;
    const u16* Vh = Vt + (size_t)head * 65536;

    const int tid = threadIdx.x;
    const int lane = tid & 63, wave = tid >> 6;
    const int l31 = lane & 31, hi = lane >> 5;
    const int q0 = qt * 256 + wave * 64;
    const int cx = l31 & 7;  // chunk-swizzle term (row&7 == l31&7 for our reads)

    // staging decode (hoisted element offsets into the per-head K / V arrays)
    int offK[4], offV[4];
#pragma unroll
    for (int i = 0; i < 4; i++) {
        const int p = tid + i * 256;
        const int kr = p >> 3, kc = (p & 7) ^ (kr & 7);     // K: 8 chunks/row
        offK[i] = kr * 64 + kc * 8;
        const int vr = p >> 4, vc = (p & 15) ^ (vr & 7);    // V: 16 chunks/row
        offV[i] = vr * 1024 + vc * 8;
    }

#define STAGE(B, K0)                                                            \
    {                                                                           \
        _Pragma("unroll") for (int i_ = 0; i_ < 4; i_++) {                      \
            const int p_ = tid + i_ * 256;                                      \
            gload16(&Kh[(size_t)(K0) * 64 + offK[i_]], &Kl[B][p_ * 8]);         \
        }                                                                       \
        _Pragma("unroll") for (int i_ = 0; i_ < 4; i_++) {                      \
            const int p_ = tid + i_ * 256;                                      \
            gload16(&Vh[(size_t)(K0) + offV[i_]], &Vl[B][p_ * 8]);              \
        }                                                                       \
    }

    // ones B-fragment for den = P @ ones
    union { u16 us[8]; bf16x8 v; } one;
#pragma unroll
    for (int i = 0; i < 8; i++) one.us[i] = 0x3F80;
    const bf16x8 onesf = one.v;

    // Q fragments (B-operand: col=q=lane&31, k = kk*16 + hi*8 + j), loaded once
    bf16x8 qf[2][4];
#pragma unroll
    for (int q2 = 0; q2 < 2; q2++)
#pragma unroll
        for (int kk = 0; kk < 4; kk++)
            qf[q2][kk] =
                *(const bf16x8*)&Qh[(size_t)(q0 + q2 * 32 + l31) * 64 + kk * 16 + hi * 8];

    f32x16 cacc[2][2];  // [q-tile][hd-half]
    f32x16 dacc[2];     // [q-tile] den accumulator, same C-layout as cacc
#pragma unroll
    for (int q2 = 0; q2 < 2; q2++) {
#pragma unroll
        for (int r = 0; r < 16; r++) {
            cacc[q2][0][r] = 0.f;
            cacc[q2][1][r] = 0.f;
            dacc[q2][r] = 0.f;
        }
    }

    STAGE(0, 0)  // prologue: tile kt=0 into buf 0
    __syncthreads();

    int buf = 0;

    // ---- QK for one 32-key group: 8 MFMAs into (s0,s1) ----
    auto QK = [&](int mt, f32x16& s0, f32x16& s1) {
#pragma unroll
        for (int r = 0; r < 16; r++) { s0[r] = 0.f; s1[r] = 0.f; }
        __builtin_amdgcn_s_setprio(1);
#pragma unroll
        for (int kk = 0; kk < 4; kk++) {
            const bf16x8 kf =
                *(const bf16x8*)&Kl[buf][((mt * 32 + l31) * 8 + ((2 * kk + hi) ^ cx)) * 8];
            s0 = __builtin_amdgcn_mfma_f32_32x32x16_bf16(kf, qf[0][kk], s0, 0, 0, 0);
            s1 = __builtin_amdgcn_mfma_f32_32x32x16_bf16(kf, qf[1][kk], s1, 0, 0, 0);
        }
        __builtin_amdgcn_s_setprio(0);
    };

    // ---- pack(s0,s1) -> A-frags, then PV for this mt's 32 keys ----
    auto PACKPV = [&](int mt, const f32x16& s0, const f32x16& s1) {
        // vf reads issued first: ds_read latency hides under the pack VALU
        const bf16x8 vfa0 = *(const bf16x8*)&Vl[buf][(l31 * 16 + ((4 * mt + hi) ^ cx)) * 8];
        const bf16x8 vfa1 =
            *(const bf16x8*)&Vl[buf][((32 + l31) * 16 + ((4 * mt + hi) ^ cx)) * 8];
        const bf16x8 vfb0 = *(const bf16x8*)&Vl[buf][(l31 * 16 + ((4 * mt + 2 + hi) ^ cx)) * 8];
        const bf16x8 vfb1 =
            *(const bf16x8*)&Vl[buf][((32 + l31) * 16 + ((4 * mt + 2 + hi) ^ cx)) * 8];

        bf16x8 paq[2][2];  // [q-tile][kg within mt]
#pragma unroll
        for (int q2 = 0; q2 < 2; q2++) {
            const f32x16& sc = q2 ? s1 : s0;
            const unsigned c0 = cvtpk(fmaxf(sc[0], 0.f), fmaxf(sc[1], 0.f));
            const unsigned c1 = cvtpk(fmaxf(sc[2], 0.f), fmaxf(sc[3], 0.f));
            const unsigned c2 = cvtpk(fmaxf(sc[4], 0.f), fmaxf(sc[5], 0.f));
            const unsigned c3 = cvtpk(fmaxf(sc[6], 0.f), fmaxf(sc[7], 0.f));
            const unsigned c4 = cvtpk(fmaxf(sc[8], 0.f), fmaxf(sc[9], 0.f));
            const unsigned c5 = cvtpk(fmaxf(sc[10], 0.f), fmaxf(sc[11], 0.f));
            const unsigned c6 = cvtpk(fmaxf(sc[12], 0.f), fmaxf(sc[13], 0.f));
            const unsigned c7 = cvtpk(fmaxf(sc[14], 0.f), fmaxf(sc[15], 0.f));
            const u32x2 s02 = __builtin_amdgcn_permlane32_swap(c0, c2, false, false);
            const u32x2 s13 = __builtin_amdgcn_permlane32_swap(c1, c3, false, false);
            const u32x2 s46 = __builtin_amdgcn_permlane32_swap(c4, c6, false, false);
            const u32x2 s57 = __builtin_amdgcn_permlane32_swap(c5, c7, false, false);
            union { unsigned u[4]; bf16x8 v; } f0u, f1u;
            f0u.u[0] = s02.x; f0u.u[1] = s13.x; f0u.u[2] = s02.y; f0u.u[3] = s13.y;
            f1u.u[0] = s46.x; f1u.u[1] = s57.x; f1u.u[2] = s46.y; f1u.u[3] = s57.y;
            paq[q2][0] = f0u.v;  // keys mt*32 + 0..15
            paq[q2][1] = f1u.v;  // keys mt*32 + 16..31
        }

        __builtin_amdgcn_s_setprio(1);
        dacc[0] = __builtin_amdgcn_mfma_f32_32x32x16_bf16(paq[0][0], onesf, dacc[0], 0, 0, 0);
        cacc[0][0] = __builtin_amdgcn_mfma_f32_32x32x16_bf16(paq[0][0], vfa0, cacc[0][0], 0, 0, 0);
        cacc[0][1] = __builtin_amdgcn_mfma_f32_32x32x16_bf16(paq[0][0], vfa1, cacc[0][1], 0, 0, 0);
        dacc[1] = __builtin_amdgcn_mfma_f32_32x32x16_bf16(paq[1][0], onesf, dacc[1], 0, 0, 0);
        cacc[1][0] = __builtin_amdgcn_mfma_f32_32x32x16_bf16(paq[1][0], vfa0, cacc[1][0], 0, 0, 0);
        cacc[1][1] = __builtin_amdgcn_mfma_f32_32x32x16_bf16(paq[1][0], vfa1, cacc[1][1], 0, 0, 0);
        dacc[0] = __builtin_amdgcn_mfma_f32_32x32x16_bf16(paq[0][1], onesf, dacc[0], 0, 0, 0);
        cacc[0][0] = __builtin_amdgcn_mfma_f32_32x32x16_bf16(paq[0][1], vfb0, cacc[0][0], 0, 0, 0);
        cacc[0][1] = __builtin_amdgcn_mfma_f32_32x32x16_bf16(paq[0][1], vfb1, cacc[0][1], 0, 0, 0);
        dacc[1] = __builtin_amdgcn_mfma_f32_32x32x16_bf16(paq[1][1], onesf, dacc[1], 0, 0, 0);
        cacc[1][0] = __builtin_amdgcn_mfma_f32_32x32x16_bf16(paq[1][1], vfb0, cacc[1][0], 0, 0, 0);
        cacc[1][1] = __builtin_amdgcn_mfma_f32_32x32x16_bf16(paq[1][1], vfb1, cacc[1][1], 0, 0, 0);
        __builtin_amdgcn_s_setprio(0);
    };

    for (int kt = 0; kt < 8; kt++) {
        if (kt < 7) STAGE(buf ^ 1, (kt + 1) * 128)  // prefetch next tile (hides under compute)

        // 2-stage pipeline: pack(mt) runs under the in-flight QK(mt+1) MFMAs
        f32x16 s0A, s1A, s0B, s1B;
        QK(0, s0A, s1A);
        QK(1, s0B, s1B);
        PACKPV(0, s0A, s1A);
        QK(2, s0A, s1A);
        PACKPV(1, s0B, s1B);
        QK(3, s0B, s1B);
        PACKPV(2, s0A, s1A);
        PACKPV(3, s0B, s1B);

        __syncthreads();  // drains this wave's prefetch DMA + guards buffer reuse
        buf ^= 1;
    }
#undef STAGE

    // ---- normalize + write ctx in (s, tok, h*64+hd) layout ----
    // dacc reg r carries den for the SAME q-row as cacc reg r (lane-local).
#pragma unroll
    for (int q2 = 0; q2 < 2; q2++) {
#pragma unroll
        for (int r = 0; r < 16; r++) {
            const int ql = (r & 3) + 8 * (r >> 2) + 4 * hi;  // q-row of reg r
            const float inv = 1.f / (dacc[q2][r] + 1e-6f);
            const size_t grow = (size_t)(s * 1024 + q0 + q2 * 32 + ql);
            Ctx[grow * 512 + h * 64 + l31] = f2b(cacc[q2][0][r] * inv);
            Ctx[grow * 512 + h * 64 + 32 + l31] = f2b(cacc[q2][1][r] * inv);
        }
    }
}

extern "C" void kernel_launch(void* const* d_in, const int* in_sizes, int n_in, void* d_out,
                              int out_size, void* d_ws, size_t ws_size, hipStream_t stream) {
    const float* x = (const float*)d_in[0];
    const float* wq = (const float*)d_in[1];
    const float* bq = (const float*)d_in[2];
    const float* wk = (const float*)d_in[3];
    const float* bk = (const float*)d_in[4];
    const float* wv = (const float*)d_in[5];
    const float* bv = (const float*)d_in[6];
    const float* wo = (const float*)d_in[7];
    const float* bo = (const float*)d_in[8];

    const size_t E = 16384ull * 512ull;
    u16* xb = (u16*)d_ws;  // bf16 x; aliased as ctx after gemm0 consumes it
    u16* cw = xb;
    u16* wb = xb + E;      // bf16 wq|wk|wv|wo
    u16* qw = wb + 4 * 262144;
    u16* kw = qw + E;
    u16* vw = kw + E;

    conv_kernel<<<dim3(4096 + 512), 256, 0, stream>>>(x, wq, wk, wv, wo, xb, wb);
    gemm_kernel<0><<<dim3(128, 12), 256, 0, stream>>>(xb, wb, bq, bk, bv, qw, kw, vw);
    attn_kernel<<<dim3(512), 256, 0, stream>>>(qw, kw, vw, cw);
    gemm_kernel<1><<<dim3(128, 4), 256, 0, stream>>>(cw, wb + 3 * 262144, bo, nullptr, nullptr,
                                                     d_out, nullptr, nullptr);
}

// Round 8
// 185.193 us; speedup vs baseline: 1.0438x; 1.0438x over previous
//
#include <hip/hip_runtime.h>

typedef unsigned short u16;
typedef __attribute__((ext_vector_type(8))) short bf16x8;
typedef __attribute__((ext_vector_type(4))) float f32x4;
typedef __attribute__((ext_vector_type(16))) float f32x16;
typedef __attribute__((ext_vector_type(2))) unsigned int u32x2;

__device__ inline u16 f2b(float f) {
    unsigned u;
    __builtin_memcpy(&u, &f, 4);
    unsigned r = u + 0x7FFF + ((u >> 16) & 1);  // RNE
    return (u16)(r >> 16);
}

__device__ inline bf16x8 pack8(const float* p) {
    union { u16 us[8]; bf16x8 v; } r;
#pragma unroll
    for (int i = 0; i < 8; i++) r.us[i] = f2b(p[i]);
    return r.v;
}

// packed 2xf32 -> 2xbf16 (RNE), src0 -> low half
__device__ inline unsigned cvtpk(float lo, float hi) {
    unsigned r;
    asm("v_cvt_pk_bf16_f32 %0, %1, %2" : "=v"(r) : "v"(lo), "v"(hi));
    return r;
}

// async global->LDS, 16B per lane. LDS dest is wave-uniform base + lane*16;
// the GLOBAL source per lane is arbitrary (this is what makes the XOR-swizzle
// staging below possible).
__device__ inline void gload16(const void* g, void* l) {
    __builtin_amdgcn_global_load_lds((__attribute__((address_space(1))) void*)g,
                                     (__attribute__((address_space(3))) void*)l, 16, 0, 0);
}

// ---------------------------------------------------------------------------
// One-shot fp32 -> bf16: x (4096 blocks) then wq,wk,wv,wo (128 each) into wb.
// ---------------------------------------------------------------------------
__global__ __launch_bounds__(256) void conv_kernel(const float* __restrict__ x,
                                                   const float* __restrict__ wq,
                                                   const float* __restrict__ wk,
                                                   const float* __restrict__ wv,
                                                   const float* __restrict__ wo,
                                                   u16* __restrict__ xb, u16* __restrict__ wb) {
    const int bid = blockIdx.x;
    const float* src;
    u16* dst;
    size_t base;
    if (bid < 4096) {
        src = x; dst = xb; base = (size_t)bid * 2048;
    } else {
        const int wsel = (bid - 4096) >> 7;
        src = (wsel == 0) ? wq : (wsel == 1) ? wk : (wsel == 2) ? wv : wo;
        dst = wb + (size_t)wsel * 262144;
        base = (size_t)((bid - 4096) & 127) * 2048;
    }
    const size_t idx = base + (size_t)threadIdx.x * 8;
    float a[8];
    *(float4*)&a[0] = *(const float4*)&src[idx];
    *(float4*)&a[4] = *(const float4*)&src[idx + 4];
    *(bf16x8*)&dst[idx] = pack8(a);
}

// ---------------------------------------------------------------------------
// bf16 GEMM v3: C[m][n] = sum_k A[m][k]*W[n][k] + bias[n].
// 128x128 tile, 4 waves; v2's dbuf+prefetch+swizzle, with BK 32 -> 64:
//   - 32 MFMAs between barriers (was 16), 8 barriers (was 16), 2x prefetch
//     window per DMA batch (the exact change that helped attn v10);
//   - BK=64 swizzle: row stride = 8 chunks, bank-quad = chunk (row drops
//     out mod 8) -> XOR row&7: stage ssc=(cl&7)^(row&7), frag read chunk
//     (kk*4+quad)^(col&7); 2-way per 16-lane group = free.
// LDS 64KB -> still 2 blocks/CU.
// MODE 0: N=1536 (q|k|v rows of wb); scatter Q*0.125,K -> (s,h,tok,hd),
//         V -> transposed (s,h,hd,tok). MODE 1: fp32 row-major out (d_out).
// ---------------------------------------------------------------------------
template <int MODE>
__global__ __launch_bounds__(256) void gemm_kernel(const u16* __restrict__ A,
                                                   const u16* __restrict__ W,
                                                   const float* __restrict__ B0,
                                                   const float* __restrict__ B1,
                                                   const float* __restrict__ B2,
                                                   void* __restrict__ O0v, u16* __restrict__ O1,
                                                   u16* __restrict__ O2) {
    const int m0 = blockIdx.x * 128;
    const int n0 = blockIdx.y * 128;
    const int seg = (MODE == 0) ? (n0 >> 9) : 0;
    const int nl0 = (MODE == 0) ? (n0 & 511) : n0;
    const float* Bb = (seg == 0) ? B0 : (seg == 1) ? B1 : B2;
    u16* O = (seg == 0) ? (u16*)O0v : (seg == 1) ? O1 : O2;

    __shared__ __align__(16) u16 Al[2][128 * 64];
    __shared__ __align__(16) u16 Bl[2][128 * 64];

    const int tid = threadIdx.x;
    const int lane = tid & 63, wave = tid >> 6;
    const int quad = lane >> 4, col = lane & 15;
    const int wm = wave >> 1, wn = wave & 1;

    // staging decode (hoisted): cl -> row, swizzled source chunk offset
    int srow[4], ssc[4];
#pragma unroll
    for (int i = 0; i < 4; i++) {
        const int cl = tid + i * 256;            // 0..1023: row = cl>>3, chunk = cl&7
        srow[i] = cl >> 3;
        ssc[i] = ((cl & 7) ^ (srow[i] & 7)) * 8;
    }
    const int c7 = col & 7;  // frag-read swizzle term (row&7 == col&7)

#define GSTAGE(BUF, K0)                                                                     \
    {                                                                                       \
        _Pragma("unroll") for (int i_ = 0; i_ < 4; i_++) {                                  \
            const int cl_ = tid + i_ * 256;                                                 \
            gload16(&A[(size_t)(m0 + srow[i_]) * 512 + (K0) + ssc[i_]], &Al[BUF][cl_ * 8]); \
        }                                                                                   \
        _Pragma("unroll") for (int i_ = 0; i_ < 4; i_++) {                                  \
            const int cl_ = tid + i_ * 256;                                                 \
            gload16(&W[(size_t)(n0 + srow[i_]) * 512 + (K0) + ssc[i_]], &Bl[BUF][cl_ * 8]); \
        }                                                                                   \
    }

    f32x4 acc[4][4];
#pragma unroll
    for (int i = 0; i < 4; i++)
#pragma unroll
        for (int j = 0; j < 4; j++) acc[i][j] = (f32x4){0.f, 0.f, 0.f, 0.f};

    GSTAGE(0, 0)  // prologue
    __syncthreads();

    int bufi = 0;
    for (int k0 = 0; k0 < 512; k0 += 64) {
        if (k0 < 448) GSTAGE(bufi ^ 1, k0 + 64)  // prefetch overlaps compute below

#pragma unroll
        for (int kk = 0; kk < 2; kk++) {
            bf16x8 af[4], bfr[4];
#pragma unroll
            for (int t = 0; t < 4; t++) {
                af[t] = *(const bf16x8*)&Al[bufi][((wm * 64 + t * 16 + col) * 8 +
                                                  ((kk * 4 + quad) ^ c7)) * 8];
                bfr[t] = *(const bf16x8*)&Bl[bufi][((wn * 64 + t * 16 + col) * 8 +
                                                    ((kk * 4 + quad) ^ c7)) * 8];
            }
            __builtin_amdgcn_s_setprio(1);
#pragma unroll
            for (int i = 0; i < 4; i++)
#pragma unroll
                for (int j = 0; j < 4; j++)
                    acc[i][j] =
                        __builtin_amdgcn_mfma_f32_16x16x32_bf16(af[i], bfr[j], acc[i][j], 0, 0, 0);
            __builtin_amdgcn_s_setprio(0);
        }
        __syncthreads();  // prefetch DMA drained here (overlapped with the MFMAs above)
        bufi ^= 1;
    }
#undef GSTAGE

    float bias[4];
#pragma unroll
    for (int j = 0; j < 4; j++) bias[j] = Bb[nl0 + wn * 64 + j * 16 + col];

#pragma unroll
    for (int i = 0; i < 4; i++) {
        const int mbase = m0 + wm * 64 + i * 16 + quad * 4;
#pragma unroll
        for (int j = 0; j < 4; j++) {
            const int nl = nl0 + wn * 64 + j * 16 + col;
            if (MODE == 1) {
                float* Of = (float*)O0v;  // fp32 final output
#pragma unroll
                for (int r = 0; r < 4; r++)
                    Of[(size_t)(mbase + r) * 512 + nl] = acc[i][j][r] + bias[j];
            } else {
                const int h = nl >> 6, hd = nl & 63;
                if (seg < 2) {
                    const float qs = (seg == 0) ? 0.125f : 1.f;  // pre-scale Q by 1/sqrt(64)
#pragma unroll
                    for (int r = 0; r < 4; r++) {
                        int m = mbase + r;
                        int s = m >> 10, tok = m & 1023;
                        O[(size_t)((s * 8 + h) * 1024 + tok) * 64 + hd] =
                            f2b((acc[i][j][r] + bias[j]) * qs);
                    }
                } else {
                    // V transposed: ((s*8+h)*64 + hd)*1024 + tok
                    int s = mbase >> 10, tok0 = mbase & 1023;
                    union { u16 us[4]; uint2 v; } pk;
#pragma unroll
                    for (int r = 0; r < 4; r++) pk.us[r] = f2b(acc[i][j][r] + bias[j]);
                    *(uint2*)&O[(size_t)((s * 8 + h) * 64 + hd) * 1024 + tok0] = pk.v;
                }
            }
        }
    }
}

// ---------------------------------------------------------------------------
// Attention v12 = v10 (proven 46.4us) + zf zero-C trick: the first QK MFMA
// of each mt consumes a loop-invariant zero register tuple instead of 32
// v_movs re-initializing s0/s1 (1024 movs/wave removed from the co-critical
// VALU pipe; +16 VGPR). v11's 2-stage pipeline REVERTED: it spilled
// (WRITE_SIZE +4.6MB scratch traffic, MfmaUtil 36->31, dur 46.4->52.5).
// 512 blocks x 4 waves, QBLK=64/wave, KVBLK=128, 2 blocks/CU, LDS 64KB.
// ---------------------------------------------------------------------------
__global__ __launch_bounds__(256, 2) void attn_kernel(const u16* __restrict__ Q,
                                                      const u16* __restrict__ Kp,
                                                      const u16* __restrict__ Vt,
                                                      u16* __restrict__ Ctx) {
    __shared__ __align__(16) u16 Kl[2][8192];  // [buf][128 keys x 64 hd], swizzled chunks
    __shared__ __align__(16) u16 Vl[2][8192];  // [buf][64 hd  x 128 tok], swizzled chunks

    const int bid = blockIdx.x;
    const int head = bid & 127;  // same-head blocks == mod 8 -> same XCD L2
    const int qt = bid >> 7;     // 0..3, 256 q-rows each
    const int s = head >> 3, h = head & 7;
    const u16* Qh = Q + (size_t)head * 65536;
    const u16* Kh = Kp + (size_t)head * 65536;
    const u16* Vh = Vt + (size_t)head * 65536;

    const int tid = threadIdx.x;
    const int lane = tid & 63, wave = tid >> 6;
    const int l31 = lane & 31, hi = lane >> 5;
    const int q0 = qt * 256 + wave * 64;
    const int cx = l31 & 7;  // chunk-swizzle term (row&7 == l31&7 for our reads)

    // staging decode (hoisted element offsets into the per-head K / V arrays)
    int offK[4], offV[4];
#pragma unroll
    for (int i = 0; i < 4; i++) {
        const int p = tid + i * 256;
        const int kr = p >> 3, kc = (p & 7) ^ (kr & 7);     // K: 8 chunks/row
        offK[i] = kr * 64 + kc * 8;
        const int vr = p >> 4, vc = (p & 15) ^ (vr & 7);    // V: 16 chunks/row
        offV[i] = vr * 1024 + vc * 8;
    }

#define STAGE(B, K0)                                                            \
    {                                                                           \
        _Pragma("unroll") for (int i_ = 0; i_ < 4; i_++) {                      \
            const int p_ = tid + i_ * 256;                                      \
            gload16(&Kh[(size_t)(K0) * 64 + offK[i_]], &Kl[B][p_ * 8]);         \
        }                                                                       \
        _Pragma("unroll") for (int i_ = 0; i_ < 4; i_++) {                      \
            const int p_ = tid + i_ * 256;                                      \
            gload16(&Vh[(size_t)(K0) + offV[i_]], &Vl[B][p_ * 8]);              \
        }                                                                       \
    }

    // ones B-fragment for den = P @ ones
    union { u16 us[8]; bf16x8 v; } one;
#pragma unroll
    for (int i = 0; i < 8; i++) one.us[i] = 0x3F80;
    const bf16x8 onesf = one.v;

    // loop-invariant zero accumulator (C-operand of each mt's first QK MFMA)
    f32x16 zf;
#pragma unroll
    for (int r = 0; r < 16; r++) zf[r] = 0.f;

    // Q fragments (B-operand: col=q=lane&31, k = kk*16 + hi*8 + j), loaded once
    bf16x8 qf[2][4];
#pragma unroll
    for (int q2 = 0; q2 < 2; q2++)
#pragma unroll
        for (int kk = 0; kk < 4; kk++)
            qf[q2][kk] =
                *(const bf16x8*)&Qh[(size_t)(q0 + q2 * 32 + l31) * 64 + kk * 16 + hi * 8];

    f32x16 cacc[2][2];  // [q-tile][hd-half]
    f32x16 dacc[2];     // [q-tile] den accumulator, same C-layout as cacc
#pragma unroll
    for (int q2 = 0; q2 < 2; q2++) {
#pragma unroll
        for (int r = 0; r < 16; r++) {
            cacc[q2][0][r] = 0.f;
            cacc[q2][1][r] = 0.f;
            dacc[q2][r] = 0.f;
        }
    }

    STAGE(0, 0)  // prologue: tile kt=0 into buf 0
    __syncthreads();

    int buf = 0;
    for (int kt = 0; kt < 8; kt++) {
        if (kt < 7) STAGE(buf ^ 1, (kt + 1) * 128)  // prefetch next tile (hides under compute)

#pragma unroll
        for (int mt = 0; mt < 4; mt++) {
            // ---- S^T = K*Q^T for 32 keys x both q-tiles (kf reused) ----
            f32x16 s0, s1;
            __builtin_amdgcn_s_setprio(1);
#pragma unroll
            for (int kk = 0; kk < 4; kk++) {
                const bf16x8 kf =
                    *(const bf16x8*)&Kl[buf][((mt * 32 + l31) * 8 + ((2 * kk + hi) ^ cx)) * 8];
                s0 = __builtin_amdgcn_mfma_f32_32x32x16_bf16(kf, qf[0][kk], kk ? s0 : zf, 0, 0, 0);
                s1 = __builtin_amdgcn_mfma_f32_32x32x16_bf16(kf, qf[1][kk], kk ? s1 : zf, 0, 0, 0);
            }
            __builtin_amdgcn_s_setprio(0);

            // ---- relu + pack to bf16 A-frags (proven permlane path) ----
            bf16x8 paq[2][2];  // [q-tile][kg within mt]
#pragma unroll
            for (int q2 = 0; q2 < 2; q2++) {
                const f32x16& sc = q2 ? s1 : s0;
                const unsigned c0 = cvtpk(fmaxf(sc[0], 0.f), fmaxf(sc[1], 0.f));
                const unsigned c1 = cvtpk(fmaxf(sc[2], 0.f), fmaxf(sc[3], 0.f));
                const unsigned c2 = cvtpk(fmaxf(sc[4], 0.f), fmaxf(sc[5], 0.f));
                const unsigned c3 = cvtpk(fmaxf(sc[6], 0.f), fmaxf(sc[7], 0.f));
                const unsigned c4 = cvtpk(fmaxf(sc[8], 0.f), fmaxf(sc[9], 0.f));
                const unsigned c5 = cvtpk(fmaxf(sc[10], 0.f), fmaxf(sc[11], 0.f));
                const unsigned c6 = cvtpk(fmaxf(sc[12], 0.f), fmaxf(sc[13], 0.f));
                const unsigned c7 = cvtpk(fmaxf(sc[14], 0.f), fmaxf(sc[15], 0.f));
                const u32x2 s02 = __builtin_amdgcn_permlane32_swap(c0, c2, false, false);
                const u32x2 s13 = __builtin_amdgcn_permlane32_swap(c1, c3, false, false);
                const u32x2 s46 = __builtin_amdgcn_permlane32_swap(c4, c6, false, false);
                const u32x2 s57 = __builtin_amdgcn_permlane32_swap(c5, c7, false, false);
                union { unsigned u[4]; bf16x8 v; } f0u, f1u;
                f0u.u[0] = s02.x; f0u.u[1] = s13.x; f0u.u[2] = s02.y; f0u.u[3] = s13.y;
                f1u.u[0] = s46.x; f1u.u[1] = s57.x; f1u.u[2] = s46.y; f1u.u[3] = s57.y;
                paq[q2][0] = f0u.v;  // keys mt*32 + 0..15
                paq[q2][1] = f1u.v;  // keys mt*32 + 16..31
            }

            // ---- ctx += P@V, den += P@ones for this mt's 2 key-groups ----
            const bf16x8 vfa0 = *(const bf16x8*)&Vl[buf][(l31 * 16 + ((4 * mt + hi) ^ cx)) * 8];
            const bf16x8 vfa1 =
                *(const bf16x8*)&Vl[buf][((32 + l31) * 16 + ((4 * mt + hi) ^ cx)) * 8];
            const bf16x8 vfb0 =
                *(const bf16x8*)&Vl[buf][(l31 * 16 + ((4 * mt + 2 + hi) ^ cx)) * 8];
            const bf16x8 vfb1 =
                *(const bf16x8*)&Vl[buf][((32 + l31) * 16 + ((4 * mt + 2 + hi) ^ cx)) * 8];
            __builtin_amdgcn_s_setprio(1);
            dacc[0] = __builtin_amdgcn_mfma_f32_32x32x16_bf16(paq[0][0], onesf, dacc[0], 0, 0, 0);
            cacc[0][0] = __builtin_amdgcn_mfma_f32_32x32x16_bf16(paq[0][0], vfa0, cacc[0][0], 0, 0, 0);
            cacc[0][1] = __builtin_amdgcn_mfma_f32_32x32x16_bf16(paq[0][0], vfa1, cacc[0][1], 0, 0, 0);
            dacc[1] = __builtin_amdgcn_mfma_f32_32x32x16_bf16(paq[1][0], onesf, dacc[1], 0, 0, 0);
            cacc[1][0] = __builtin_amdgcn_mfma_f32_32x32x16_bf16(paq[1][0], vfa0, cacc[1][0], 0, 0, 0);
            cacc[1][1] = __builtin_amdgcn_mfma_f32_32x32x16_bf16(paq[1][0], vfa1, cacc[1][1], 0, 0, 0);
            dacc[0] = __builtin_amdgcn_mfma_f32_32x32x16_bf16(paq[0][1], onesf, dacc[0], 0, 0, 0);
            cacc[0][0] = __builtin_amdgcn_mfma_f32_32x32x16_bf16(paq[0][1], vfb0, cacc[0][0], 0, 0, 0);
            cacc[0][1] = __builtin_amdgcn_mfma_f32_32x32x16_bf16(paq[0][1], vfb1, cacc[0][1], 0, 0, 0);
            dacc[1] = __builtin_amdgcn_mfma_f32_32x32x16_bf16(paq[1][1], onesf, dacc[1], 0, 0, 0);
            cacc[1][0] = __builtin_amdgcn_mfma_f32_32x32x16_bf16(paq[1][1], vfb0, cacc[1][0], 0, 0, 0);
            cacc[1][1] = __builtin_amdgcn_mfma_f32_32x32x16_bf16(paq[1][1], vfb1, cacc[1][1], 0, 0, 0);
            __builtin_amdgcn_s_setprio(0);
        }

        __syncthreads();  // drains this wave's prefetch DMA + guards buffer reuse
        buf ^= 1;
    }
#undef STAGE

    // ---- normalize + write ctx in (s, tok, h*64+hd) layout ----
    // dacc reg r carries den for the SAME q-row as cacc reg r (lane-local).
#pragma unroll
    for (int q2 = 0; q2 < 2; q2++) {
#pragma unroll
        for (int r = 0; r < 16; r++) {
            const int ql = (r & 3) + 8 * (r >> 2) + 4 * hi;  // q-row of reg r
            const float inv = 1.f / (dacc[q2][r] + 1e-6f);
            const size_t grow = (size_t)(s * 1024 + q0 + q2 * 32 + ql);
            Ctx[grow * 512 + h * 64 + l31] = f2b(cacc[q2][0][r] * inv);
            Ctx[grow * 512 + h * 64 + 32 + l31] = f2b(cacc[q2][1][r] * inv);
        }
    }
}

extern "C" void kernel_launch(void* const* d_in, const int* in_sizes, int n_in, void* d_out,
                              int out_size, void* d_ws, size_t ws_size, hipStream_t stream) {
    const float* x = (const float*)d_in[0];
    const float* wq = (const float*)d_in[1];
    const float* bq = (const float*)d_in[2];
    const float* wk = (const float*)d_in[3];
    const float* bk = (const float*)d_in[4];
    const float* wv = (const float*)d_in[5];
    const float* bv = (const float*)d_in[6];
    const float* wo = (const float*)d_in[7];
    const float* bo = (const float*)d_in[8];

    const size_t E = 16384ull * 512ull;
    u16* xb = (u16*)d_ws;  // bf16 x; aliased as ctx after gemm0 consumes it
    u16* cw = xb;
    u16* wb = xb + E;      // bf16 wq|wk|wv|wo
    u16* qw = wb + 4 * 262144;
    u16* kw = qw + E;
    u16* vw = kw + E;

    conv_kernel<<<dim3(4096 + 512), 256, 0, stream>>>(x, wq, wk, wv, wo, xb, wb);
    gemm_kernel<0><<<dim3(128, 12), 256, 0, stream>>>(xb, wb, bq, bk, bv, qw, kw, vw);
    attn_kernel<<<dim3(512), 256, 0, stream>>>(qw, kw, vw, cw);
    gemm_kernel<1><<<dim3(128, 4), 256, 0, stream>>>(cw, wb + 3 * 262144, bo, nullptr, nullptr,
                                                     d_out, nullptr, nullptr);
}